// Round 14
// baseline (73.860 us; speedup 1.0000x reference)
//
#include <hip/hip_runtime.h>

// QuantizedConv2d: N=32, CIN=128, H=W=56, COUT=256, 3x3, pad=1 (zp=-3), stride 1.
// Round 14: REVERT r13 fusion (regressed: in-conv transpose cost > serial
// prepass). New levers: (1) conv 512-thr blocks (8 waves, 224px x 128cout),
// __launch_bounds__(512,4) -> 16 waves/CU (prior configs ran ~8; TLP was the
// untested axis); (2) bias/wscale hoisted before K-loop; (3) halo fill fused
// into pack_x (disjoint bytes). Core per-wave tile unchanged: 112px x 32cout,
// acc[7][2], XOR-swizzled LDS-A, B global->reg depth-1 prefetch, ONE barrier.

typedef __attribute__((ext_vector_type(4))) int i32x4;

#define NB_N 32
#define CIN 128
#define HH 56
#define WW 56
#define PH 58                              // padded H/W
#define COUT 256
#define PIX_PER_IMG (HH*WW)                // 3136
#define X_IMG_INTS (PIX_PER_IMG*CIN)
#define XP_ROW_BYTES (PH*CIN)              // 7424
#define XP_IMG_BYTES (PH*XP_ROW_BYTES)     // 430592
#define XQ_PAD_BYTES ((size_t)NB_N*XP_IMG_BYTES)
#define A_BYTES (6*XP_ROW_BYTES)           // 44544

// ---------------- pack_x: NCHW int32 -> padded NHWC int8 (+ fused halo) ----------------
// Register-packed word transpose: 8 coalesced int4 loads -> pack 4 channel
// bytes per word -> word stores into WPR=33 tile (<=2-way bank = free).
#define WPR 33   // words per w-row (132 B)
__global__ __launch_bounds__(256) void pack_x_kernel(const int* __restrict__ x,
                                                     signed char* __restrict__ xq) {
    __shared__ int tile[WW * WPR];           // 7392 B
    int nh = blockIdx.x;                     // 0..N*H-1
    int n = nh / HH, h = nh - n * HH;
    const int* src = x + (size_t)n * X_IMG_INTS + h * WW;  // (n, c, h, 0)
    signed char* img = xq + (size_t)n * XP_IMG_BYTES;
    int q = threadIdx.x & 15;                // w-quad (0..13 valid)
    int cg4 = threadIdx.x >> 4;              // 0..15
    if (q < 14) {
#pragma unroll
        for (int i = 0; i < 2; ++i) {
            int cg = cg4 + i * 16;           // channel group 0..31
            i32x4 v0 = *(const i32x4*)(src + (cg * 4 + 0) * PIX_PER_IMG + q * 4);
            i32x4 v1 = *(const i32x4*)(src + (cg * 4 + 1) * PIX_PER_IMG + q * 4);
            i32x4 v2 = *(const i32x4*)(src + (cg * 4 + 2) * PIX_PER_IMG + q * 4);
            i32x4 v3 = *(const i32x4*)(src + (cg * 4 + 3) * PIX_PER_IMG + q * 4);
#pragma unroll
            for (int j = 0; j < 4; ++j) {
                int word = (v0[j] & 255) | ((v1[j] & 255) << 8) |
                           ((v2[j] & 255) << 16) | (v3[j] << 24);
                tile[(q * 4 + j) * WPR + cg] = word;
            }
        }
    }
    // fused halo (disjoint bytes from interior writes):
    const i32x4 pad = {(int)0xFDFDFDFD, (int)0xFDFDFDFD, (int)0xFDFDFDFD, (int)0xFDFDFDFD};
    {   // side pads of this row (h+1): w=0 and w=57, 128 B each = 8 x 16B
        int t = threadIdx.x;
        if (t < 16) {
            int w = (t >> 3) ? 57 : 0;
            *(i32x4*)(img + ((size_t)(h + 1) * PH + w) * CIN + (t & 7) * 16) = pad;
        }
    }
    if (h == 0) {       // top pad row 0: 7424 B = 464 x 16B
        for (int t = threadIdx.x; t < 464; t += 256)
            *(i32x4*)(img + (size_t)t * 16) = pad;
    }
    if (h == HH - 1) {  // bottom pad row 57
        for (int t = threadIdx.x; t < 464; t += 256)
            *(i32x4*)(img + (size_t)57 * XP_ROW_BYTES + t * 16) = pad;
    }
    __syncthreads();
    int* dst = (int*)(img + ((size_t)(h + 1) * PH + 1) * CIN);
#pragma unroll
    for (int i = 0; i < 7; ++i) {
        int t = i * 256 + threadIdx.x;
        int w = t >> 5, c4 = t & 31;
        dst[w * 32 + c4] = tile[w * WPR + c4];
    }
}

// ---------------- pack_w: OIHW int32 -> fragment-ordered int8 ----------------
// frag f = (tap*2 + kb)*16 + nfrag; byte = f*1024 + lane*16 + j
// -> weight[cout = nf*16 + (lane&15)][cin = kb*64 + (lane>>4)*16 + j][kh][kw]
__global__ __launch_bounds__(256) void pack_w_kernel(const int* __restrict__ w,
                                                     signed char* __restrict__ wq) {
    int idx = blockIdx.x * 256 + threadIdx.x;    // 0..18431
    if (idx >= 9 * 2 * 16 * 64) return;
    int lane = idx & 63;
    int fid = idx >> 6;
    int t = fid / 32;
    int rem = fid - t * 32;
    int kb = rem >> 4;
    int nf = rem & 15;
    int cout = nf * 16 + (lane & 15);
    int cinb = kb * 64 + (lane >> 4) * 16;
    int kh = t / 3, kw = t - kh * 3;
    union { signed char b[16]; i32x4 v; } u;
#pragma unroll
    for (int j = 0; j < 16; ++j) {
        int cin = cinb + j;
        u.b[j] = (signed char)w[((cout * CIN + cin) * 3 + kh) * 3 + kw];
    }
    *(i32x4*)(wq + (size_t)idx * 16) = u.v;
}

// ---------------- conv: LDS-A + global-reg-B implicit GEMM, ONE barrier ----------------
// grid = 896 blocks x 512 thr: img n (32) x rowblk rb (14, 4 rows) x couthalf cb (2).
// 8 waves: (pxhalf = wv>>2, cquad = wv&3). Wave: 112 px x 32 couts; acc[7][2].
__global__ __launch_bounds__(512, 4) void conv_kernel(const signed char* __restrict__ xq,
                                                      const signed char* __restrict__ wq,
                                                      const int* __restrict__ bias,
                                                      const float* __restrict__ wscale,
                                                      int* __restrict__ out) {
    __shared__ __align__(16) signed char lds[A_BYTES];
    const int tid = threadIdx.x;
    const int lane = tid & 63, wv = tid >> 6;
    const int row = lane & 15, grp = lane >> 4;

    // XCD-chunked swizzle: 896 = 8*112; consecutive 112 blocks (4 images) per XCD.
    int orig = (blockIdx.x & 7) * 112 + (blockIdx.x >> 3);
    int n = orig / 28;
    int rr = orig - n * 28;
    int rb = rr >> 1;          // row-block: output rows [rb*4, rb*4+4)
    int cb = rr & 1;           // cout half: [cb*128, +128)
    int pxhalf = wv >> 2, cquad = wv & 3;

    const signed char* ximg = xq + (size_t)n * XP_IMG_BYTES + (size_t)rb * 4 * XP_ROW_BYTES;

    // ---- prologue: A-halo (6 padded rows) into LDS, swizzled ----
    // LDS[d] = global[g],  g = d ^ (((d>>7)&7)<<4)   (involution on bits 4-6)
#pragma unroll
    for (int k = 0; k < 6; ++k) {
        int d = k * 8192 + tid * 16;
        if (d < A_BYTES) {
            int g = d ^ (((d >> 7) & 7) << 4);
            i32x4 v = *(const i32x4*)(ximg + g);
            *(i32x4*)(lds + d) = v;
        }
    }

    // epilogue constants hoisted BEFORE the K-loop (hide their latency here)
    float sc[2];
    int b2[2];
    const int coutbase = cb * 128 + cquad * 32;
#pragma unroll
    for (int j = 0; j < 2; ++j) {
        int cout = coutbase + j * 16 + row;
        sc[j] = wscale[cout] * 0.5f;          // 0.05/0.1 * ws
        b2[j] = 2 * bias[cout];
    }

    __syncthreads();   // the ONLY barrier

    // per-m center pixel index in halo (padded coords, rows 0..5 of halo)
    int pc[7];
#pragma unroll
    for (int m = 0; m < 7; ++m) {
        int off = pxhalf * 112 + m * 16 + row;               // 0..223
        int lr = (off >= 56) + (off >= 112) + (off >= 168);  // off/56
        int w = off - lr * 56;
        pc[m] = (lr + 1) * PH + (w + 1);
    }

    const int tapd[9] = {-PH - 1, -PH, -PH + 1, -1, 0, 1, PH - 1, PH, PH + 1};

    // B direct from global (fragment-ordered, L2-resident), 1-step prefetch.
    // Wave's 2 n-frags: nf = cb*8 + cquad*2 + {0,1}.  Step stride = 16KB.
    const signed char* wbase = wq + (size_t)(cb * 8 + cquad * 2) * 1024 + lane * 16;

    i32x4 acc[7][2] = {};
    i32x4 bn0 = *(const i32x4*)(wbase);
    i32x4 bn1 = *(const i32x4*)(wbase + 1024);

#pragma unroll
    for (int s = 0; s < 18; ++s) {
        const int t = s >> 1, kb = s & 1;
        i32x4 b0 = bn0, b1 = bn1;
        if (s < 17) {   // prefetch next step's B fragments (hidden under 14 MFMAs)
            bn0 = *(const i32x4*)(wbase + (s + 1) * 16384);
            bn1 = *(const i32x4*)(wbase + (s + 1) * 16384 + 1024);
        }
        // A ds_reads (swizzled)
        i32x4 a[7];
#pragma unroll
        for (int m = 0; m < 7; ++m) {
            int pix = pc[m] + tapd[t];
            int g = (pix << 7) + (kb << 6) + (grp << 4);
            int d = g ^ ((pix & 7) << 4);
            a[m] = *(const i32x4*)(lds + d);
        }
#pragma unroll
        for (int m = 0; m < 7; ++m) {
            acc[m][0] = __builtin_amdgcn_mfma_i32_16x16x64_i8(a[m], b0, acc[m][0], 0, 0, 0);
            acc[m][1] = __builtin_amdgcn_mfma_i32_16x16x64_i8(a[m], b1, acc[m][1], 0, 0, 0);
        }
    }

    // ---- epilogue: acc + 2*bias -> scale -> rint -> clamp -> int32 store ----
    const int pixbase = rb * 224 + pxhalf * 112;
#pragma unroll
    for (int m = 0; m < 7; ++m) {
        int pl = pixbase + m * 16 + grp * 4;  // pixel of reg 0
        size_t obase = (size_t)n * (COUT * PIX_PER_IMG) + pl;
#pragma unroll
        for (int j = 0; j < 2; ++j) {
            int cout = coutbase + j * 16 + row;
            i32x4 v;
#pragma unroll
            for (int r = 0; r < 4; ++r) {
                int o = acc[m][j][r] + b2[j];
                float f = fmaf((float)o, sc[j], 5.0f);
                f = rintf(f);                 // RNE == jnp.round
                f = fminf(fmaxf(f, -128.0f), 127.0f);
                v[r] = (int)f;
            }
            *(i32x4*)(out + obase + (size_t)cout * PIX_PER_IMG) = v;
        }
    }
}

extern "C" void kernel_launch(void* const* d_in, const int* in_sizes, int n_in,
                              void* d_out, int out_size, void* d_ws, size_t ws_size,
                              hipStream_t stream) {
    const int* x = (const int*)d_in[0];
    const int* w = (const int*)d_in[1];
    const int* bias = (const int*)d_in[2];
    const float* ws = (const float*)d_in[3];
    int* out = (int*)d_out;

    signed char* xq = (signed char*)d_ws;                 // padded NHWC int8
    signed char* wq = xq + XQ_PAD_BYTES;                  // 288 KB fragment-ordered weights

    pack_x_kernel<<<NB_N * HH, 256, 0, stream>>>(x, xq);  // halo fused in
    pack_w_kernel<<<72, 256, 0, stream>>>(w, wq);
    conv_kernel<<<896, 512, 0, stream>>>(xq, wq, bias, ws, out);
}

// Round 15
// 63.799 us; speedup vs baseline: 1.1577x; 1.1577x over previous
//
#include <hip/hip_runtime.h>

// QuantizedConv2d: N=32, CIN=128, H=W=56, COUT=256, 3x3, pad=1 (zp=-3), stride 1.
// Round 15: CONTIGUOUS-STORE epilogue. Diagnosis: conv invariant ~50us across
// all compute changes because NCHW stores scattered 16x64B per instruction
// (12.5KB cout stride) -> ~2 TB/s HBM writes (harness seq fill: 7.1 TB/s).
// Fix: after K-loop, transpose acc through the (dead) A-LDS buffer per
// cout-half pass -> b128 stores in contiguous 896B-per-cout runs.
// Core = r11 (no spill): 1792 x 256thr, (256,3), acc[7][2], XOR-swizzled
// LDS-A, B global->reg depth-1 prefetch. pack_x = word-transpose + fused halo.

typedef __attribute__((ext_vector_type(4))) int i32x4;

#define NB_N 32
#define CIN 128
#define HH 56
#define WW 56
#define PH 58                              // padded H/W
#define COUT 256
#define PIX_PER_IMG (HH*WW)                // 3136
#define X_IMG_INTS (PIX_PER_IMG*CIN)
#define XP_ROW_BYTES (PH*CIN)              // 7424
#define XP_IMG_BYTES (PH*XP_ROW_BYTES)     // 430592
#define XQ_PAD_BYTES ((size_t)NB_N*XP_IMG_BYTES)
#define A_BYTES (6*XP_ROW_BYTES)           // 44544
#define EP_STRIDE 228                      // ints per cout row in epilogue LDS (912 B)

// ---------------- pack_x: NCHW int32 -> padded NHWC int8 (+ fused halo) ----------------
#define WPR 33   // words per w-row (132 B)
__global__ __launch_bounds__(256) void pack_x_kernel(const int* __restrict__ x,
                                                     signed char* __restrict__ xq) {
    __shared__ int tile[WW * WPR];           // 7392 B
    int nh = blockIdx.x;                     // 0..N*H-1
    int n = nh / HH, h = nh - n * HH;
    const int* src = x + (size_t)n * X_IMG_INTS + h * WW;  // (n, c, h, 0)
    signed char* img = xq + (size_t)n * XP_IMG_BYTES;
    int q = threadIdx.x & 15;                // w-quad (0..13 valid)
    int cg4 = threadIdx.x >> 4;              // 0..15
    if (q < 14) {
#pragma unroll
        for (int i = 0; i < 2; ++i) {
            int cg = cg4 + i * 16;           // channel group 0..31
            i32x4 v0 = *(const i32x4*)(src + (cg * 4 + 0) * PIX_PER_IMG + q * 4);
            i32x4 v1 = *(const i32x4*)(src + (cg * 4 + 1) * PIX_PER_IMG + q * 4);
            i32x4 v2 = *(const i32x4*)(src + (cg * 4 + 2) * PIX_PER_IMG + q * 4);
            i32x4 v3 = *(const i32x4*)(src + (cg * 4 + 3) * PIX_PER_IMG + q * 4);
#pragma unroll
            for (int j = 0; j < 4; ++j) {
                int word = (v0[j] & 255) | ((v1[j] & 255) << 8) |
                           ((v2[j] & 255) << 16) | (v3[j] << 24);
                tile[(q * 4 + j) * WPR + cg] = word;
            }
        }
    }
    // fused halo (disjoint bytes from interior writes):
    const i32x4 pad = {(int)0xFDFDFDFD, (int)0xFDFDFDFD, (int)0xFDFDFDFD, (int)0xFDFDFDFD};
    {   // side pads of this row (h+1): w=0 and w=57, 128 B each = 8 x 16B
        int t = threadIdx.x;
        if (t < 16) {
            int w = (t >> 3) ? 57 : 0;
            *(i32x4*)(img + ((size_t)(h + 1) * PH + w) * CIN + (t & 7) * 16) = pad;
        }
    }
    if (h == 0) {       // top pad row 0: 7424 B = 464 x 16B
        for (int t = threadIdx.x; t < 464; t += 256)
            *(i32x4*)(img + (size_t)t * 16) = pad;
    }
    if (h == HH - 1) {  // bottom pad row 57
        for (int t = threadIdx.x; t < 464; t += 256)
            *(i32x4*)(img + (size_t)57 * XP_ROW_BYTES + t * 16) = pad;
    }
    __syncthreads();
    int* dst = (int*)(img + ((size_t)(h + 1) * PH + 1) * CIN);
#pragma unroll
    for (int i = 0; i < 7; ++i) {
        int t = i * 256 + threadIdx.x;
        int w = t >> 5, c4 = t & 31;
        dst[w * 32 + c4] = tile[w * WPR + c4];
    }
}

// ---------------- pack_w: OIHW int32 -> fragment-ordered int8 ----------------
// frag f = (tap*2 + kb)*16 + nfrag; byte = f*1024 + lane*16 + j
// -> weight[cout = nf*16 + (lane&15)][cin = kb*64 + (lane>>4)*16 + j][kh][kw]
__global__ __launch_bounds__(256) void pack_w_kernel(const int* __restrict__ w,
                                                     signed char* __restrict__ wq) {
    int idx = blockIdx.x * 256 + threadIdx.x;    // 0..18431
    if (idx >= 9 * 2 * 16 * 64) return;
    int lane = idx & 63;
    int fid = idx >> 6;
    int t = fid / 32;
    int rem = fid - t * 32;
    int kb = rem >> 4;
    int nf = rem & 15;
    int cout = nf * 16 + (lane & 15);
    int cinb = kb * 64 + (lane >> 4) * 16;
    int kh = t / 3, kw = t - kh * 3;
    union { signed char b[16]; i32x4 v; } u;
#pragma unroll
    for (int j = 0; j < 16; ++j) {
        int cin = cinb + j;
        u.b[j] = (signed char)w[((cout * CIN + cin) * 3 + kh) * 3 + kw];
    }
    *(i32x4*)(wq + (size_t)idx * 16) = u.v;
}

// ---------------- conv: LDS-A + global-reg-B implicit GEMM ----------------
// grid = 1792 blocks: img n (32) x rowblk rb (14, 4 rows) x coutblk cq (4, 64 couts).
// wave (pxhalf, chalf): 112 px (7 m-frags) x 32 couts (2 n-frags); acc[7][2].
__global__ __launch_bounds__(256, 3) void conv_kernel(const signed char* __restrict__ xq,
                                                      const signed char* __restrict__ wq,
                                                      const int* __restrict__ bias,
                                                      const float* __restrict__ wscale,
                                                      int* __restrict__ out) {
    __shared__ __align__(16) signed char lds[A_BYTES];   // A-halo, then epilogue buffer
    const int tid = threadIdx.x;
    const int lane = tid & 63, wv = tid >> 6;
    const int row = lane & 15, grp = lane >> 4;

    // XCD-chunked swizzle: 1792 = 8*224; consecutive 224 blocks (4 images) per XCD.
    int orig = (blockIdx.x & 7) * 224 + (blockIdx.x >> 3);
    int n = orig / 56;
    int rr = orig - n * 56;
    int rb = rr >> 2;          // row-block: output rows [rb*4, rb*4+4)
    int cq = rr & 3;           // cout quarter: [cq*64, +64)
    int pxhalf = wv >> 1, chalf = wv & 1;

    const signed char* ximg = xq + (size_t)n * XP_IMG_BYTES + (size_t)rb * 4 * XP_ROW_BYTES;

    // ---- prologue: A-halo (6 padded rows) into LDS, swizzled ----
    // LDS[d] = global[g],  g = d ^ (((d>>7)&7)<<4)   (involution on bits 4-6)
#pragma unroll
    for (int k = 0; k < 11; ++k) {
        int d = k * 4096 + tid * 16;
        if (d < A_BYTES) {
            int g = d ^ (((d >> 7) & 7) << 4);
            i32x4 v = *(const i32x4*)(ximg + g);
            *(i32x4*)(lds + d) = v;
        }
    }

    // epilogue constants hoisted before the K-loop
    float sc[2];
    int b2[2];
    const int coutbase = cq * 64 + chalf * 32;
#pragma unroll
    for (int j = 0; j < 2; ++j) {
        int cout = coutbase + j * 16 + row;
        sc[j] = wscale[cout] * 0.5f;          // 0.05/0.1 * ws
        b2[j] = 2 * bias[cout];
    }

    __syncthreads();

    // per-m center pixel index in halo (padded coords, rows 0..5 of halo)
    int pc[7];
#pragma unroll
    for (int m = 0; m < 7; ++m) {
        int off = pxhalf * 112 + m * 16 + row;               // 0..223
        int lr = (off >= 56) + (off >= 112) + (off >= 168);  // off/56
        int w = off - lr * 56;
        pc[m] = (lr + 1) * PH + (w + 1);
    }

    const int tapd[9] = {-PH - 1, -PH, -PH + 1, -1, 0, 1, PH - 1, PH, PH + 1};

    // B direct from global (fragment-ordered, L2-resident), 1-step prefetch.
    const signed char* wbase = wq + (size_t)(cq * 4 + chalf * 2) * 1024 + lane * 16;

    i32x4 acc[7][2] = {};
    i32x4 bn0 = *(const i32x4*)(wbase);
    i32x4 bn1 = *(const i32x4*)(wbase + 1024);

#pragma unroll
    for (int s = 0; s < 18; ++s) {
        const int t = s >> 1, kb = s & 1;
        i32x4 b0 = bn0, b1 = bn1;
        if (s < 17) {   // prefetch next step's B fragments (hidden under 14 MFMAs)
            bn0 = *(const i32x4*)(wbase + (s + 1) * 16384);
            bn1 = *(const i32x4*)(wbase + (s + 1) * 16384 + 1024);
        }
        // A ds_reads (swizzled)
        i32x4 a[7];
#pragma unroll
        for (int m = 0; m < 7; ++m) {
            int pix = pc[m] + tapd[t];
            int g = (pix << 7) + (kb << 6) + (grp << 4);
            int d = g ^ ((pix & 7) << 4);
            a[m] = *(const i32x4*)(lds + d);
        }
#pragma unroll
        for (int m = 0; m < 7; ++m) {
            acc[m][0] = __builtin_amdgcn_mfma_i32_16x16x64_i8(a[m], b0, acc[m][0], 0, 0, 0);
            acc[m][1] = __builtin_amdgcn_mfma_i32_16x16x64_i8(a[m], b1, acc[m][1], 0, 0, 0);
        }
    }

    // ---- epilogue: quantize -> LDS transpose -> CONTIGUOUS b128 stores ----
    // Pass p stages couts [cq*64 + p*32, +32) as [cl][224 px] ints (stride 228:
    // 16B-unit index u = 57*cl + px/4, u%8 = (cl+px/4)%8 -> even 8-lane/bank
    // spread in both phases = full LDS BW).
    __syncthreads();                     // all waves done with A-LDS
    int* elds = (int*)lds;
    const int pixbase = rb * 224;
    const size_t nbase = (size_t)n * (COUT * PIX_PER_IMG);
#pragma unroll
    for (int p = 0; p < 2; ++p) {
        if (chalf == p) {
#pragma unroll
            for (int m = 0; m < 7; ++m) {
                int px0 = pxhalf * 112 + m * 16 + grp * 4;
#pragma unroll
                for (int j = 0; j < 2; ++j) {
                    int cl = j * 16 + row;
                    i32x4 v;
#pragma unroll
                    for (int r = 0; r < 4; ++r) {
                        int o = acc[m][j][r] + b2[j];
                        float f = fmaf((float)o, sc[j], 5.0f);
                        f = rintf(f);                 // RNE == jnp.round
                        f = fminf(fmaxf(f, -128.0f), 127.0f);
                        v[r] = (int)f;
                    }
                    *(i32x4*)(elds + cl * EP_STRIDE + px0) = v;
                }
            }
        }
        __syncthreads();
        // all 4 waves: read back rows, store contiguous 896B-per-cout runs
#pragma unroll
        for (int rnd = 0; rnd < 7; ++rnd) {
            int tg = rnd * 256 + tid;          // 0..1791 = 32 couts x 56 quads
            int cl = tg / 56;
            int q = tg - cl * 56;
            i32x4 v = *(const i32x4*)(elds + cl * EP_STRIDE + q * 4);
            int cout = cq * 64 + p * 32 + cl;
            *(i32x4*)(out + nbase + (size_t)cout * PIX_PER_IMG + pixbase + q * 4) = v;
        }
        __syncthreads();
    }
}

extern "C" void kernel_launch(void* const* d_in, const int* in_sizes, int n_in,
                              void* d_out, int out_size, void* d_ws, size_t ws_size,
                              hipStream_t stream) {
    const int* x = (const int*)d_in[0];
    const int* w = (const int*)d_in[1];
    const int* bias = (const int*)d_in[2];
    const float* ws = (const float*)d_in[3];
    int* out = (int*)d_out;

    signed char* xq = (signed char*)d_ws;                 // padded NHWC int8
    signed char* wq = xq + XQ_PAD_BYTES;                  // 288 KB fragment-ordered weights

    pack_x_kernel<<<NB_N * HH, 256, 0, stream>>>(x, xq);  // halo fused in
    pack_w_kernel<<<72, 256, 0, stream>>>(w, wq);
    conv_kernel<<<1792, 256, 0, stream>>>(xq, wq, bias, ws, out);
}